// Round 1
// 262.074 us; speedup vs baseline: 1.0231x; 1.0231x over previous
//
#include <hip/hip_runtime.h>

#define N_NODES   100000
#define N_EDGES   1600000
#define IN_DIM    128
#define HID_DIM   64
#define N_CLASSES 40

#define NBUCK 782          // ceil(100000 / 128) coarse buckets, bucket = row >> 7
#define BCAP  2816         // bucket capacity incl. pad-to-4
#define EPB   6400         // edges per block in pass A
#define PBLK  1024         // part_a block size
#define G1BLK 1563         // gemm1 sub-grid inside fused part_b+gemm1 launch

typedef __attribute__((ext_vector_type(8))) short bf16x8;
typedef __attribute__((ext_vector_type(4))) float f32x4;

__device__ inline short f2bf(float f) {
    unsigned u = __float_as_uint(f);
    unsigned r = (u + 0x7FFFu + ((u >> 16) & 1u)) >> 16;   // RNE
    return (short)r;
}
__device__ inline float bflo(unsigned w) { return __uint_as_float(w << 16); }
__device__ inline float bfhi(unsigned w) { return __uint_as_float(w & 0xFFFF0000u); }
// packed edge: bits[16:0] = col, bits[31:17] = val as unsigned bf15 (sign dropped, vals >= 0)
__device__ inline float upval(unsigned w) { return __uint_as_float((w >> 17) << 16); }

// ---------------- weight prep (+ bcnt zero) ----------------
// W1t bf16 [64][128]; Mt = (W2@Wc)^T bf16 [64][64] (rows 40..63 zero); bv = b2@Wc fp32 [40]
__global__ __launch_bounds__(256) void prep_weights(const float* __restrict__ W1,
                                                    const float* __restrict__ W2,
                                                    const float* __restrict__ Wc,
                                                    const float* __restrict__ b2,
                                                    short* __restrict__ W1t,
                                                    short* __restrict__ Mt,
                                                    float* __restrict__ bv,
                                                    int* __restrict__ bcnt) {
    for (int i = blockIdx.x * 256 + threadIdx.x; i < IN_DIM * HID_DIM; i += gridDim.x * 256) {
        int n = i >> 7, k = i & 127;
        W1t[i] = f2bf(W1[k * HID_DIM + n]);
    }
    if (blockIdx.x == 7) {
        for (int i = threadIdx.x; i < NBUCK; i += 256) bcnt[i] = 0;
    }
    if (blockIdx.x == 0) {
        for (int idx = threadIdx.x; idx < HID_DIM * HID_DIM; idx += 256) {
            int n = idx >> 6, i = idx & 63;        // Mt[n][i] = M[i][n] = sum_j W2[i][j]*Wc[j][n]
            float acc = 0.f;
            if (n < N_CLASSES)
                for (int j = 0; j < HID_DIM; ++j)
                    acc = fmaf(W2[i * HID_DIM + j], Wc[j * N_CLASSES + n], acc);
            Mt[n * HID_DIM + i] = f2bf(acc);
        }
        for (int n = threadIdx.x; n < N_CLASSES; n += 256) {
            float acc = 0.f;
            for (int j = 0; j < HID_DIM; ++j)
                acc = fmaf(b2[j], Wc[j * N_CLASSES + n], acc);
            bv[n] = acc;
        }
    }
}

// ---------------- Pass A v4: LDS-staged bucket sort, bf15 compression moved here ----------------
// payload: x = (localrow7 << 17) | col17 ; y = (valbf15 << 10) | bucket10
__global__ __launch_bounds__(PBLK) void part_a(const int* __restrict__ erow,
                                               const int* __restrict__ ecol,
                                               const float* __restrict__ eval,
                                               int* __restrict__ bcnt,
                                               int2* __restrict__ tmp) {
    __shared__ int2 pay[EPB];                                    // 51.2 KB
    __shared__ int hist[NBUCK], lbase[NBUCK], cur[NBUCK], dofs[NBUCK], scan[NBUCK]; // 15.6 KB
    int e0 = blockIdx.x * EPB;
    int tid = threadIdx.x;
    for (int i = tid; i < NBUCK; i += PBLK) { hist[i] = 0; cur[i] = 0; }
    __syncthreads();
    for (int i = tid; i < EPB; i += PBLK)
        atomicAdd(&hist[erow[e0 + i] >> 7], 1);
    __syncthreads();
    for (int i = tid; i < NBUCK; i += PBLK) {
        int n = hist[i];
        dofs[i] = i * BCAP + (n ? atomicAdd(&bcnt[i], n) : 0);
        scan[i] = n;
    }
    __syncthreads();
    for (int off = 1; off < NBUCK; off <<= 1) {
        int t = 0;
        if (tid < NBUCK && tid >= off) t = scan[tid - off];
        __syncthreads();
        if (tid < NBUCK) scan[tid] += t;
        __syncthreads();
    }
    if (tid < NBUCK) {
        lbase[tid] = scan[tid] - hist[tid];
        dofs[tid] -= lbase[tid];
    }
    __syncthreads();
    for (int i = tid; i < EPB; i += PBLK) {
        int e = e0 + i;
        int r = erow[e];
        int b = r >> 7;
        int p = lbase[b] + atomicAdd(&cur[b], 1);
        unsigned u = __float_as_uint(eval[e]);
        unsigned vb = ((u + 0x7FFFu + ((u >> 16) & 1u)) >> 16) & 0x7FFFu;  // bf15 RNE, sign dropped
        pay[p] = make_int2(((r & 127) << 17) | ecol[e], (int)((vb << 10) | (unsigned)b));
    }
    __syncthreads();
    for (int p = tid; p < EPB; p += PBLK) {
        int2 v = pay[p];
        int b = (unsigned)v.y & 1023u;
        int dest = dofs[b] + p;
        if (dest < (b + 1) * BCAP)
            tmp[dest] = v;
    }
}

// ---------------- fused: Pass B (blocks < NBUCK) || GEMM1 MFMA (blocks >= NBUCK) ----------------
// Pass B: sort bucket by local row, pad to mult-of-4, pack to 4 B
// GEMM1:  hbf[n,64] = bf16(x[n,128] @ W1 + b1)   (independent of the edge sort)
__global__ __launch_bounds__(256) void part_b_gemm1(const int* __restrict__ bcnt,
                                                    const int2* __restrict__ tmp,
                                                    unsigned* __restrict__ tmp2,
                                                    int2* __restrict__ rowmeta,
                                                    const float* __restrict__ x,
                                                    const short* __restrict__ W1t,
                                                    const float* __restrict__ b1,
                                                    unsigned short* __restrict__ outH) {
    __shared__ int2 ein[BCAP];           // 22.5 KB
    __shared__ unsigned eout[BCAP];      // 11.3 KB
    __shared__ int hist[128], pad[128], basep[128], cur[128], scan[128];
    if (blockIdx.x < NBUCK) {
        // ---------- Pass B ----------
        int b = blockIdx.x;
        int nb = bcnt[b]; if (nb > BCAP) nb = BCAP;
        for (int i = threadIdx.x; i < nb; i += 256) ein[i] = tmp[(size_t)b * BCAP + i];
        if (threadIdx.x < 128) { hist[threadIdx.x] = 0; cur[threadIdx.x] = 0; }
        __syncthreads();
        for (int i = threadIdx.x; i < nb; i += 256)
            atomicAdd(&hist[(ein[i].x >> 17) & 127], 1);
        __syncthreads();
        if (threadIdx.x < 128) {
            pad[threadIdx.x] = (hist[threadIdx.x] + 3) & ~3;     // pad to mult-of-4
            scan[threadIdx.x] = pad[threadIdx.x];
        }
        __syncthreads();
        for (int off = 1; off < 128; off <<= 1) {
            int t = 0;
            if (threadIdx.x < 128 && threadIdx.x >= off) t = scan[threadIdx.x - off];
            __syncthreads();
            if (threadIdx.x < 128) scan[threadIdx.x] += t;
            __syncthreads();
        }
        if (threadIdx.x < 128) basep[threadIdx.x] = scan[threadIdx.x] - pad[threadIdx.x];
        __syncthreads();
        int ntot = scan[127]; if (ntot > BCAP) ntot = BCAP;
        for (int i = threadIdx.x; i < nb; i += 256) {
            int lr = (ein[i].x >> 17) & 127;
            int p = basep[lr] + atomicAdd(&cur[lr], 1);
            if (p < BCAP) {
                unsigned vb = ((unsigned)ein[i].y >> 10) & 0x7FFFu;      // already bf15
                eout[p] = (vb << 17) | (unsigned)(ein[i].x & 0x1FFFF);
            }
        }
        __syncthreads();
        if (threadIdx.x < 128) {
            int pe = basep[threadIdx.x] + pad[threadIdx.x];
            for (int p = basep[threadIdx.x] + hist[threadIdx.x]; p < pe && p < BCAP; ++p)
                eout[p] = 0u;                 // col 0, val +0.0
        }
        __syncthreads();
        for (int i = threadIdx.x; i < ntot; i += 256) tmp2[(size_t)b * BCAP + i] = eout[i];
        if (threadIdx.x < 128) {
            int r = b * 128 + threadIdx.x;
            if (r < N_NODES)
                rowmeta[r] = make_int2(b * BCAP + basep[threadIdx.x], pad[threadIdx.x]);
        }
    } else {
        // ---------- GEMM1 (MFMA) ----------
        int gb = blockIdx.x - NBUCK;
        int wave = threadIdx.x >> 6;
        int lane = threadIdx.x & 63;
        int node0 = gb * 64 + wave * 16;
        if (node0 >= N_NODES) return;
        int m = lane & 15;
        int q = lane >> 4;
        const float* xrow = x + (size_t)(node0 + m) * IN_DIM;
        f32x4 acc0 = {0,0,0,0}, acc1 = {0,0,0,0}, acc2 = {0,0,0,0}, acc3 = {0,0,0,0};
#pragma unroll
        for (int kb = 0; kb < 4; ++kb) {
            int k0 = kb * 32 + q * 8;
            float4 a0 = *(const float4*)(xrow + k0);
            float4 a1 = *(const float4*)(xrow + k0 + 4);
            bf16x8 af;
            af[0]=f2bf(a0.x); af[1]=f2bf(a0.y); af[2]=f2bf(a0.z); af[3]=f2bf(a0.w);
            af[4]=f2bf(a1.x); af[5]=f2bf(a1.y); af[6]=f2bf(a1.z); af[7]=f2bf(a1.w);
            bf16x8 bf0 = *(const bf16x8*)(W1t + ( 0 + m) * IN_DIM + k0);
            bf16x8 bf1 = *(const bf16x8*)(W1t + (16 + m) * IN_DIM + k0);
            bf16x8 bf2 = *(const bf16x8*)(W1t + (32 + m) * IN_DIM + k0);
            bf16x8 bf3 = *(const bf16x8*)(W1t + (48 + m) * IN_DIM + k0);
            acc0 = __builtin_amdgcn_mfma_f32_16x16x32_bf16(af, bf0, acc0, 0, 0, 0);
            acc1 = __builtin_amdgcn_mfma_f32_16x16x32_bf16(af, bf1, acc1, 0, 0, 0);
            acc2 = __builtin_amdgcn_mfma_f32_16x16x32_bf16(af, bf2, acc2, 0, 0, 0);
            acc3 = __builtin_amdgcn_mfma_f32_16x16x32_bf16(af, bf3, acc3, 0, 0, 0);
        }
        f32x4 accs[4] = {acc0, acc1, acc2, acc3};
#pragma unroll
        for (int t = 0; t < 4; ++t) {
            float bias = b1[t * 16 + m];
#pragma unroll
            for (int r = 0; r < 4; ++r) {
                int node = node0 + q * 4 + r;            // C/D: col=lane&15, row=q*4+r
                outH[(size_t)node * HID_DIM + t * 16 + m] = (unsigned short)f2bf(accs[t][r] + bias);
            }
        }
    }
}

// ---------------- GEMM2u (MFMA): u[n,64] = bf16(relu(hbf[n,64]) @ M)  (no bias) ----------------
__global__ __launch_bounds__(256) void gemm2u_mfma(const unsigned short* __restrict__ h,
                                                   const short* __restrict__ Mt,
                                                   unsigned short* __restrict__ out) {
    int wave = threadIdx.x >> 6;
    int lane = threadIdx.x & 63;
    int node0 = blockIdx.x * 64 + wave * 16;
    if (node0 >= N_NODES) return;
    int m = lane & 15;
    int q = lane >> 4;
    const unsigned short* hrow = h + (size_t)(node0 + m) * HID_DIM;
    f32x4 acc0 = {0,0,0,0}, acc1 = {0,0,0,0}, acc2 = {0,0,0,0}, acc3 = {0,0,0,0};
#pragma unroll
    for (int kb = 0; kb < 2; ++kb) {
        int k0 = kb * 32 + q * 8;
        bf16x8 af = *(const bf16x8*)(hrow + k0);
#pragma unroll
        for (int j = 0; j < 8; ++j)
            af[j] = ((unsigned short)af[j] & 0x8000u) ? 0 : af[j];   // bf16 ReLU
        bf16x8 bf0 = *(const bf16x8*)(Mt + ( 0 + m) * HID_DIM + k0);
        bf16x8 bf1 = *(const bf16x8*)(Mt + (16 + m) * HID_DIM + k0);
        bf16x8 bf2 = *(const bf16x8*)(Mt + (32 + m) * HID_DIM + k0);
        bf16x8 bf3 = *(const bf16x8*)(Mt + (48 + m) * HID_DIM + k0);
        acc0 = __builtin_amdgcn_mfma_f32_16x16x32_bf16(af, bf0, acc0, 0, 0, 0);
        acc1 = __builtin_amdgcn_mfma_f32_16x16x32_bf16(af, bf1, acc1, 0, 0, 0);
        acc2 = __builtin_amdgcn_mfma_f32_16x16x32_bf16(af, bf2, acc2, 0, 0, 0);
        acc3 = __builtin_amdgcn_mfma_f32_16x16x32_bf16(af, bf3, acc3, 0, 0, 0);
    }
    f32x4 accs[4] = {acc0, acc1, acc2, acc3};
#pragma unroll
    for (int t = 0; t < 4; ++t) {
#pragma unroll
        for (int r = 0; r < 4; ++r) {
            int node = node0 + q * 4 + r;
            out[(size_t)node * HID_DIM + t * 16 + m] = (unsigned short)f2bf(accs[t][r]);
        }
    }
}

// ---------------- SpMM v5: one row per 8-lane subgroup, LDS meta staging, no shuffles ----------------
// lane = (s = lane>>3: row within wave, dq = lane&7: dim octet). 16 B/lane gathers.
// deg is a multiple of 4 (pad-to-4); staging + uint4 meta loop handle any mult-of-4 degree.
__global__ __launch_bounds__(256) void spmm_csr(const int2* __restrict__ rowmeta,
                                                const unsigned* __restrict__ ecv,
                                                const unsigned short* __restrict__ dense,
                                                unsigned short* __restrict__ out) {
    __shared__ unsigned lm[4][8][68];    // 8.7 KB; stride 68 words: 16B-aligned rows, <=2-way banks
    int wave = threadIdx.x >> 6;
    int lane = threadIdx.x & 63;
    int s = lane >> 3, dq = lane & 7;
    int r = (blockIdx.x * 4 + wave) * 8 + s;   // 3125 * 4 * 8 == 100000
    int2 meta = rowmeta[r];
    int beg = meta.x, deg = meta.y;            // deg multiple of 4 (maybe 0)
    int degc = deg < 64 ? deg : 64;
    for (int e = dq; e < degc; e += 8)         // stage this row's packed edges
        lm[wave][s][e] = ecv[beg + e];
    __syncthreads();
    const unsigned* mp = lm[wave][s];
    float a0=0,a1=0,a2=0,a3=0,a4=0,a5=0,a6=0,a7=0;
    if (deg > 0) {
        uint4 w = *(const uint4*)mp;           // deg>0 => deg>=4, safe
        for (int e = 0; e < degc; e += 4) {
            uint4 wn = (e + 4 < degc) ? *(const uint4*)(mp + e + 4) : w;   // 1-ahead meta (lgkm)
            uint4 g0 = *(const uint4*)(dense + ((size_t)(w.x & 0x1FFFF) << 6) + (dq << 3));
            uint4 g1 = *(const uint4*)(dense + ((size_t)(w.y & 0x1FFFF) << 6) + (dq << 3));
            uint4 g2 = *(const uint4*)(dense + ((size_t)(w.z & 0x1FFFF) << 6) + (dq << 3));
            uint4 g3 = *(const uint4*)(dense + ((size_t)(w.w & 0x1FFFF) << 6) + (dq << 3));
            float v0 = upval(w.x), v1 = upval(w.y), v2 = upval(w.z), v3 = upval(w.w);
            a0=fmaf(v0,bflo(g0.x),a0); a1=fmaf(v0,bfhi(g0.x),a1); a2=fmaf(v0,bflo(g0.y),a2); a3=fmaf(v0,bfhi(g0.y),a3);
            a4=fmaf(v0,bflo(g0.z),a4); a5=fmaf(v0,bfhi(g0.z),a5); a6=fmaf(v0,bflo(g0.w),a6); a7=fmaf(v0,bfhi(g0.w),a7);
            a0=fmaf(v1,bflo(g1.x),a0); a1=fmaf(v1,bfhi(g1.x),a1); a2=fmaf(v1,bflo(g1.y),a2); a3=fmaf(v1,bfhi(g1.y),a3);
            a4=fmaf(v1,bflo(g1.z),a4); a5=fmaf(v1,bfhi(g1.z),a5); a6=fmaf(v1,bflo(g1.w),a6); a7=fmaf(v1,bfhi(g1.w),a7);
            a0=fmaf(v2,bflo(g2.x),a0); a1=fmaf(v2,bfhi(g2.x),a1); a2=fmaf(v2,bflo(g2.y),a2); a3=fmaf(v2,bfhi(g2.y),a3);
            a4=fmaf(v2,bflo(g2.z),a4); a5=fmaf(v2,bfhi(g2.z),a5); a6=fmaf(v2,bflo(g2.w),a6); a7=fmaf(v2,bfhi(g2.w),a7);
            a0=fmaf(v3,bflo(g3.x),a0); a1=fmaf(v3,bfhi(g3.x),a1); a2=fmaf(v3,bflo(g3.y),a2); a3=fmaf(v3,bfhi(g3.y),a3);
            a4=fmaf(v3,bflo(g3.z),a4); a5=fmaf(v3,bfhi(g3.z),a5); a6=fmaf(v3,bflo(g3.w),a6); a7=fmaf(v3,bfhi(g3.w),a7);
            w = wn;
        }
        for (int e = 64; e < deg; ++e) {       // rare tail (deg > 64)
            unsigned we = ecv[beg + e];
            uint4 g = *(const uint4*)(dense + ((size_t)(we & 0x1FFFF) << 6) + (dq << 3));
            float v = upval(we);
            a0=fmaf(v,bflo(g.x),a0); a1=fmaf(v,bfhi(g.x),a1); a2=fmaf(v,bflo(g.y),a2); a3=fmaf(v,bfhi(g.y),a3);
            a4=fmaf(v,bflo(g.z),a4); a5=fmaf(v,bfhi(g.z),a5); a6=fmaf(v,bflo(g.w),a6); a7=fmaf(v,bfhi(g.w),a7);
        }
    }
    uint4 o;
    o.x = (unsigned short)f2bf(a0) | ((unsigned)(unsigned short)f2bf(a1) << 16);
    o.y = (unsigned short)f2bf(a2) | ((unsigned)(unsigned short)f2bf(a3) << 16);
    o.z = (unsigned short)f2bf(a4) | ((unsigned)(unsigned short)f2bf(a5) << 16);
    o.w = (unsigned short)f2bf(a6) | ((unsigned)(unsigned short)f2bf(a7) << 16);
    *(uint4*)(out + (size_t)r * HID_DIM + (dq << 3)) = o;
}

// ---------------- SpMM2 + classifier epilogue (v5 body + intra-subgroup log-softmax) ----------------
__global__ __launch_bounds__(256) void spmm_cls(const int2* __restrict__ rowmeta,
                                                const unsigned* __restrict__ ecv,
                                                const unsigned short* __restrict__ dense,
                                                const float* __restrict__ bv,
                                                const float* __restrict__ bc,
                                                float* __restrict__ outF) {
    __shared__ unsigned lm[4][8][68];
    int wave = threadIdx.x >> 6;
    int lane = threadIdx.x & 63;
    int s = lane >> 3, dq = lane & 7;
    int r = (blockIdx.x * 4 + wave) * 8 + s;
    float4 bv0 = {0,0,0,0}, bv1 = {0,0,0,0}, bc0 = {0,0,0,0}, bc1 = {0,0,0,0};
    if (dq < 5) {
        bv0 = *(const float4*)(bv + dq * 8);  bv1 = *(const float4*)(bv + dq * 8 + 4);
        bc0 = *(const float4*)(bc + dq * 8);  bc1 = *(const float4*)(bc + dq * 8 + 4);
    }
    int2 meta = rowmeta[r];
    int beg = meta.x, deg = meta.y;
    int degc = deg < 64 ? deg : 64;
    for (int e = dq; e < degc; e += 8)
        lm[wave][s][e] = ecv[beg + e];
    __syncthreads();
    const unsigned* mp = lm[wave][s];
    float a0=0,a1=0,a2=0,a3=0,a4=0,a5=0,a6=0,a7=0, asum=0;
    if (deg > 0) {
        uint4 w = *(const uint4*)mp;
        for (int e = 0; e < degc; e += 4) {
            uint4 wn = (e + 4 < degc) ? *(const uint4*)(mp + e + 4) : w;
            uint4 g0 = *(const uint4*)(dense + ((size_t)(w.x & 0x1FFFF) << 6) + (dq << 3));
            uint4 g1 = *(const uint4*)(dense + ((size_t)(w.y & 0x1FFFF) << 6) + (dq << 3));
            uint4 g2 = *(const uint4*)(dense + ((size_t)(w.z & 0x1FFFF) << 6) + (dq << 3));
            uint4 g3 = *(const uint4*)(dense + ((size_t)(w.w & 0x1FFFF) << 6) + (dq << 3));
            float v0 = upval(w.x), v1 = upval(w.y), v2 = upval(w.z), v3 = upval(w.w);
            asum += v0 + v1 + v2 + v3;
            a0=fmaf(v0,bflo(g0.x),a0); a1=fmaf(v0,bfhi(g0.x),a1); a2=fmaf(v0,bflo(g0.y),a2); a3=fmaf(v0,bfhi(g0.y),a3);
            a4=fmaf(v0,bflo(g0.z),a4); a5=fmaf(v0,bfhi(g0.z),a5); a6=fmaf(v0,bflo(g0.w),a6); a7=fmaf(v0,bfhi(g0.w),a7);
            a0=fmaf(v1,bflo(g1.x),a0); a1=fmaf(v1,bfhi(g1.x),a1); a2=fmaf(v1,bflo(g1.y),a2); a3=fmaf(v1,bfhi(g1.y),a3);
            a4=fmaf(v1,bflo(g1.z),a4); a5=fmaf(v1,bfhi(g1.z),a5); a6=fmaf(v1,bflo(g1.w),a6); a7=fmaf(v1,bfhi(g1.w),a7);
            a0=fmaf(v2,bflo(g2.x),a0); a1=fmaf(v2,bfhi(g2.x),a1); a2=fmaf(v2,bflo(g2.y),a2); a3=fmaf(v2,bfhi(g2.y),a3);
            a4=fmaf(v2,bflo(g2.z),a4); a5=fmaf(v2,bfhi(g2.z),a5); a6=fmaf(v2,bflo(g2.w),a6); a7=fmaf(v2,bfhi(g2.w),a7);
            a0=fmaf(v3,bflo(g3.x),a0); a1=fmaf(v3,bfhi(g3.x),a1); a2=fmaf(v3,bflo(g3.y),a2); a3=fmaf(v3,bfhi(g3.y),a3);
            a4=fmaf(v3,bflo(g3.z),a4); a5=fmaf(v3,bfhi(g3.z),a5); a6=fmaf(v3,bflo(g3.w),a6); a7=fmaf(v3,bfhi(g3.w),a7);
            w = wn;
        }
        for (int e = 64; e < deg; ++e) {
            unsigned we = ecv[beg + e];
            uint4 g = *(const uint4*)(dense + ((size_t)(we & 0x1FFFF) << 6) + (dq << 3));
            float v = upval(we);
            asum += v;
            a0=fmaf(v,bflo(g.x),a0); a1=fmaf(v,bfhi(g.x),a1); a2=fmaf(v,bflo(g.y),a2); a3=fmaf(v,bfhi(g.y),a3);
            a4=fmaf(v,bflo(g.z),a4); a5=fmaf(v,bfhi(g.z),a5); a6=fmaf(v,bflo(g.w),a6); a7=fmaf(v,bfhi(g.w),a7);
        }
    }
    // logits for this lane's dim octet (asum is complete per-lane; no reduction needed)
    float l0 = fmaf(asum, bv0.x, a0) + bc0.x;
    float l1 = fmaf(asum, bv0.y, a1) + bc0.y;
    float l2 = fmaf(asum, bv0.z, a2) + bc0.z;
    float l3 = fmaf(asum, bv0.w, a3) + bc0.w;
    float l4 = fmaf(asum, bv1.x, a4) + bc1.x;
    float l5 = fmaf(asum, bv1.y, a5) + bc1.y;
    float l6 = fmaf(asum, bv1.z, a6) + bc1.z;
    float l7 = fmaf(asum, bv1.w, a7) + bc1.w;
    float mx = -1e30f;
    if (dq < 5)
        mx = fmaxf(fmaxf(fmaxf(l0, l1), fmaxf(l2, l3)),
                   fmaxf(fmaxf(l4, l5), fmaxf(l6, l7)));
#pragma unroll
    for (int off = 1; off < 8; off <<= 1) mx = fmaxf(mx, __shfl_xor(mx, off));
    float ss = 0.f;
    if (dq < 5)
        ss = __expf(l0 - mx) + __expf(l1 - mx) + __expf(l2 - mx) + __expf(l3 - mx)
           + __expf(l4 - mx) + __expf(l5 - mx) + __expf(l6 - mx) + __expf(l7 - mx);
#pragma unroll
    for (int off = 1; off < 8; off <<= 1) ss += __shfl_xor(ss, off);
    float lse = mx + __logf(ss);
    if (dq < 5) {
        float4 o0 = {l0 - lse, l1 - lse, l2 - lse, l3 - lse};
        float4 o1 = {l4 - lse, l5 - lse, l6 - lse, l7 - lse};
        float* dst = outF + (size_t)r * N_CLASSES + dq * 8;
        *(float4*)(dst) = o0;
        *(float4*)(dst + 4) = o1;
    }
}

extern "C" void kernel_launch(void* const* d_in, const int* in_sizes, int n_in,
                              void* d_out, int out_size, void* d_ws, size_t ws_size,
                              hipStream_t stream) {
    const float* x    = (const float*)d_in[0];
    const int*   erow = (const int*)  d_in[1];
    const int*   ecol = (const int*)  d_in[2];
    const float* eval = (const float*)d_in[3];
    const float* W1   = (const float*)d_in[4];
    const float* b1   = (const float*)d_in[5];
    const float* W2   = (const float*)d_in[6];
    const float* b2   = (const float*)d_in[7];
    const float* Wc   = (const float*)d_in[8];
    const float* bc   = (const float*)d_in[9];
    float* out = (float*)d_out;

    // ---- workspace layout ----
    char* ws = (char*)d_ws;
    size_t off = 0;
    auto alloc = [&](size_t bytes) { char* p = ws + off; off += (bytes + 255) & ~(size_t)255; return p; };
    unsigned short* bufA = (unsigned short*)alloc((size_t)N_NODES * HID_DIM * sizeof(short)); // 12.8 MB
    unsigned short* bufB = (unsigned short*)alloc((size_t)N_NODES * HID_DIM * sizeof(short)); // 12.8 MB
    int2*     tmp     = (int2*)    alloc((size_t)NBUCK * BCAP * sizeof(int2));     // 17.6 MB
    unsigned* tmp2    = (unsigned*)alloc((size_t)NBUCK * BCAP * sizeof(unsigned)); //  8.8 MB
    int2*     rowmeta = (int2*)    alloc((size_t)N_NODES * sizeof(int2));          //  0.8 MB
    int*      bcnt    = (int*)     alloc(NBUCK * sizeof(int));
    short*    W1t     = (short*)   alloc((size_t)IN_DIM * HID_DIM * sizeof(short));
    short*    Mt      = (short*)   alloc((size_t)HID_DIM * HID_DIM * sizeof(short));
    float*    bv      = (float*)   alloc(64 * sizeof(float));

    const int tile_grid = (N_NODES + 63) / 64;       // 1563
    const int spmm_grid = N_NODES / 32;              // 3125 (4 waves x 8 rows, exact)
    const int grid_a    = (N_EDGES + EPB - 1) / EPB; // 250

    // ---- build bucketed packed CSR + weight prep (bcnt zeroed inside prep) ----
    prep_weights<<<8, 256, 0, stream>>>(W1, W2, Wc, b2, W1t, Mt, bv, bcnt);
    part_a<<<grid_a, PBLK, 0, stream>>>(erow, ecol, eval, bcnt, tmp);
    // fused: part_b (blocks 0..NBUCK-1) runs concurrently with gemm1 (blocks NBUCK..NBUCK+1562)
    part_b_gemm1<<<NBUCK + tile_grid, 256, 0, stream>>>(bcnt, tmp, tmp2, rowmeta,
                                                        x, W1t, b1, bufA);
    // ---- layer 1 aggregate ----
    spmm_csr<<<spmm_grid, 256, 0, stream>>>(rowmeta, tmp2, bufA, bufB);
    // ---- layer 2 folded with classifier: u = relu(h)@(W2@Wc); fused aggregate+softmax ----
    gemm2u_mfma<<<tile_grid, 256, 0, stream>>>(bufB, Mt, bufA);
    spmm_cls<<<spmm_grid, 256, 0, stream>>>(rowmeta, tmp2, bufA, bv, bc, out);
}

// Round 2
// 232.320 us; speedup vs baseline: 1.1542x; 1.1281x over previous
//
#include <hip/hip_runtime.h>

#define N_NODES   100000
#define N_EDGES   1600000
#define IN_DIM    128
#define HID_DIM   64
#define N_CLASSES 40

#define NBUCK 782          // ceil(100000 / 128) coarse buckets, bucket = row >> 7
#define BCAP  2816         // bucket capacity incl. pad-to-4
#define EPB   6400         // edges per block in pass A
#define PBLK  1024         // part_a block size
#define GRID_A 250         // N_EDGES / EPB exactly

typedef __attribute__((ext_vector_type(8))) short bf16x8;
typedef __attribute__((ext_vector_type(4))) float f32x4;

__device__ inline short f2bf(float f) {
    unsigned u = __float_as_uint(f);
    unsigned r = (u + 0x7FFFu + ((u >> 16) & 1u)) >> 16;   // RNE
    return (short)r;
}
__device__ inline float bflo(unsigned w) { return __uint_as_float(w << 16); }
__device__ inline float bfhi(unsigned w) { return __uint_as_float(w & 0xFFFF0000u); }
// packed edge: bits[16:0] = col, bits[31:17] = val as unsigned bf15 (sign dropped, vals >= 0)
__device__ inline float upval(unsigned w) { return __uint_as_float((w >> 17) << 16); }

// ---------------- fused: weight prep (blocks >= GRID_A) || Pass A bucket sort ----------------
// prep: W1t bf16 [64][128]; Mt = (W2@Wc)^T bf16 [64][64] (rows 40..63 zero); bv = b2@Wc fp32 [40]
// part_a payload: x = (localrow7 << 17) | col17 ; y = (valbf15 << 10) | bucket10
// bcnt must be zeroed by hipMemsetAsync BEFORE this kernel (cross-block ordering).
__global__ __launch_bounds__(PBLK) void prep_parta(const int* __restrict__ erow,
                                                   const int* __restrict__ ecol,
                                                   const float* __restrict__ eval,
                                                   int* __restrict__ bcnt,
                                                   int2* __restrict__ tmp,
                                                   const float* __restrict__ W1,
                                                   const float* __restrict__ W2,
                                                   const float* __restrict__ Wc,
                                                   const float* __restrict__ b2,
                                                   short* __restrict__ W1t,
                                                   short* __restrict__ Mt,
                                                   float* __restrict__ bv) {
    __shared__ int2 pay[EPB];                                    // 51.2 KB
    __shared__ int hist[NBUCK], lbase[NBUCK], cur[NBUCK], dofs[NBUCK], scan[NBUCK]; // 15.6 KB
    int tid = threadIdx.x;
    if (blockIdx.x >= GRID_A) {
        // ---------- weight prep (8 blocks) ----------
        int pb = blockIdx.x - GRID_A;
        {   // W1t: 8192 entries, exactly one per thread across 8 blocks
            int i = pb * PBLK + tid;
            int n = i >> 7, k = i & 127;
            W1t[i] = f2bf(W1[k * HID_DIM + n]);
        }
        if (pb == 0) {
            for (int idx = tid; idx < HID_DIM * HID_DIM; idx += PBLK) {
                int n = idx >> 6, i = idx & 63;    // Mt[n][i] = M[i][n] = sum_j W2[i][j]*Wc[j][n]
                float acc = 0.f;
                if (n < N_CLASSES)
                    for (int j = 0; j < HID_DIM; ++j)
                        acc = fmaf(W2[i * HID_DIM + j], Wc[j * N_CLASSES + n], acc);
                Mt[n * HID_DIM + i] = f2bf(acc);
            }
        }
        if (pb == 1 && tid < N_CLASSES) {
            float acc = 0.f;
            for (int j = 0; j < HID_DIM; ++j)
                acc = fmaf(b2[j], Wc[j * N_CLASSES + tid], acc);
            bv[tid] = acc;
        }
        return;
    }
    // ---------- Pass A ----------
    int e0 = blockIdx.x * EPB;
    for (int i = tid; i < NBUCK; i += PBLK) { hist[i] = 0; cur[i] = 0; }
    __syncthreads();
    for (int i = tid; i < EPB; i += PBLK)
        atomicAdd(&hist[erow[e0 + i] >> 7], 1);
    __syncthreads();
    for (int i = tid; i < NBUCK; i += PBLK) {
        int n = hist[i];
        dofs[i] = i * BCAP + (n ? atomicAdd(&bcnt[i], n) : 0);
        scan[i] = n;
    }
    __syncthreads();
    for (int off = 1; off < NBUCK; off <<= 1) {
        int t = 0;
        if (tid < NBUCK && tid >= off) t = scan[tid - off];
        __syncthreads();
        if (tid < NBUCK) scan[tid] += t;
        __syncthreads();
    }
    if (tid < NBUCK) {
        lbase[tid] = scan[tid] - hist[tid];
        dofs[tid] -= lbase[tid];
    }
    __syncthreads();
    for (int i = tid; i < EPB; i += PBLK) {
        int e = e0 + i;
        int r = erow[e];
        int b = r >> 7;
        int p = lbase[b] + atomicAdd(&cur[b], 1);
        unsigned u = __float_as_uint(eval[e]);
        unsigned vb = ((u + 0x7FFFu + ((u >> 16) & 1u)) >> 16) & 0x7FFFu;  // bf15 RNE, sign dropped
        pay[p] = make_int2(((r & 127) << 17) | ecol[e], (int)((vb << 10) | (unsigned)b));
    }
    __syncthreads();
    for (int p = tid; p < EPB; p += PBLK) {
        int2 v = pay[p];
        int b = (unsigned)v.y & 1023u;
        int dest = dofs[b] + p;
        if (dest < (b + 1) * BCAP)
            tmp[dest] = v;
    }
}

// ---------------- fused: Pass B (blocks < NBUCK) || GEMM1 MFMA (blocks >= NBUCK) ----------------
// Pass B: sort bucket by local row, pad to mult-of-4, pack to 4 B
// GEMM1:  hbf[n,64] = bf16(x[n,128] @ W1 + b1)   (independent of the edge sort)
__global__ __launch_bounds__(256) void part_b_gemm1(const int* __restrict__ bcnt,
                                                    const int2* __restrict__ tmp,
                                                    unsigned* __restrict__ tmp2,
                                                    int2* __restrict__ rowmeta,
                                                    const float* __restrict__ x,
                                                    const short* __restrict__ W1t,
                                                    const float* __restrict__ b1,
                                                    unsigned short* __restrict__ outH) {
    __shared__ int2 ein[BCAP];           // 22.5 KB
    __shared__ unsigned eout[BCAP];      // 11.3 KB
    __shared__ int hist[128], pad[128], basep[128], cur[128], scan[128];
    if (blockIdx.x < NBUCK) {
        // ---------- Pass B ----------
        int b = blockIdx.x;
        int nb = bcnt[b]; if (nb > BCAP) nb = BCAP;
        for (int i = threadIdx.x; i < nb; i += 256) ein[i] = tmp[(size_t)b * BCAP + i];
        if (threadIdx.x < 128) { hist[threadIdx.x] = 0; cur[threadIdx.x] = 0; }
        __syncthreads();
        for (int i = threadIdx.x; i < nb; i += 256)
            atomicAdd(&hist[(ein[i].x >> 17) & 127], 1);
        __syncthreads();
        if (threadIdx.x < 128) {
            pad[threadIdx.x] = (hist[threadIdx.x] + 3) & ~3;     // pad to mult-of-4
            scan[threadIdx.x] = pad[threadIdx.x];
        }
        __syncthreads();
        for (int off = 1; off < 128; off <<= 1) {
            int t = 0;
            if (threadIdx.x < 128 && threadIdx.x >= off) t = scan[threadIdx.x - off];
            __syncthreads();
            if (threadIdx.x < 128) scan[threadIdx.x] += t;
            __syncthreads();
        }
        if (threadIdx.x < 128) basep[threadIdx.x] = scan[threadIdx.x] - pad[threadIdx.x];
        __syncthreads();
        int ntot = scan[127]; if (ntot > BCAP) ntot = BCAP;
        for (int i = threadIdx.x; i < nb; i += 256) {
            int lr = (ein[i].x >> 17) & 127;
            int p = basep[lr] + atomicAdd(&cur[lr], 1);
            if (p < BCAP) {
                unsigned vb = ((unsigned)ein[i].y >> 10) & 0x7FFFu;      // already bf15
                eout[p] = (vb << 17) | (unsigned)(ein[i].x & 0x1FFFF);
            }
        }
        __syncthreads();
        if (threadIdx.x < 128) {
            int pe = basep[threadIdx.x] + pad[threadIdx.x];
            for (int p = basep[threadIdx.x] + hist[threadIdx.x]; p < pe && p < BCAP; ++p)
                eout[p] = 0u;                 // col 0, val +0.0
        }
        __syncthreads();
        for (int i = threadIdx.x; i < ntot; i += 256) tmp2[(size_t)b * BCAP + i] = eout[i];
        if (threadIdx.x < 128) {
            int r = b * 128 + threadIdx.x;
            if (r < N_NODES)
                rowmeta[r] = make_int2(b * BCAP + basep[threadIdx.x], pad[threadIdx.x]);
        }
    } else {
        // ---------- GEMM1 (MFMA) ----------
        int gb = blockIdx.x - NBUCK;
        int wave = threadIdx.x >> 6;
        int lane = threadIdx.x & 63;
        int node0 = gb * 64 + wave * 16;
        if (node0 >= N_NODES) return;
        int m = lane & 15;
        int q = lane >> 4;
        const float* xrow = x + (size_t)(node0 + m) * IN_DIM;
        f32x4 acc0 = {0,0,0,0}, acc1 = {0,0,0,0}, acc2 = {0,0,0,0}, acc3 = {0,0,0,0};
#pragma unroll
        for (int kb = 0; kb < 4; ++kb) {
            int k0 = kb * 32 + q * 8;
            float4 a0 = *(const float4*)(xrow + k0);
            float4 a1 = *(const float4*)(xrow + k0 + 4);
            bf16x8 af;
            af[0]=f2bf(a0.x); af[1]=f2bf(a0.y); af[2]=f2bf(a0.z); af[3]=f2bf(a0.w);
            af[4]=f2bf(a1.x); af[5]=f2bf(a1.y); af[6]=f2bf(a1.z); af[7]=f2bf(a1.w);
            bf16x8 bf0 = *(const bf16x8*)(W1t + ( 0 + m) * IN_DIM + k0);
            bf16x8 bf1 = *(const bf16x8*)(W1t + (16 + m) * IN_DIM + k0);
            bf16x8 bf2 = *(const bf16x8*)(W1t + (32 + m) * IN_DIM + k0);
            bf16x8 bf3 = *(const bf16x8*)(W1t + (48 + m) * IN_DIM + k0);
            acc0 = __builtin_amdgcn_mfma_f32_16x16x32_bf16(af, bf0, acc0, 0, 0, 0);
            acc1 = __builtin_amdgcn_mfma_f32_16x16x32_bf16(af, bf1, acc1, 0, 0, 0);
            acc2 = __builtin_amdgcn_mfma_f32_16x16x32_bf16(af, bf2, acc2, 0, 0, 0);
            acc3 = __builtin_amdgcn_mfma_f32_16x16x32_bf16(af, bf3, acc3, 0, 0, 0);
        }
        f32x4 accs[4] = {acc0, acc1, acc2, acc3};
#pragma unroll
        for (int t = 0; t < 4; ++t) {
            float bias = b1[t * 16 + m];
#pragma unroll
            for (int r = 0; r < 4; ++r) {
                int node = node0 + q * 4 + r;            // C/D: col=lane&15, row=q*4+r
                outH[(size_t)node * HID_DIM + t * 16 + m] = (unsigned short)f2bf(accs[t][r] + bias);
            }
        }
    }
}

// ---------------- SpMM1 + fused layer-2 matmul ----------------
// Gather loop identical to proven v5. Epilogue: h = relu(agg) -> bf16 -> XOR-swizzled LDS
// [32 nodes][64 dims], barrier, then u = h @ M via 4 MFMAs/wave, store u directly.
// This replaces the separate gemm2u pass (saves one dispatch + 25.6 MB round-trip);
// numerics identical (relu commutes with bf16 RNE rounding for this path).
__global__ __launch_bounds__(256) void spmm1_mm(const int2* __restrict__ rowmeta,
                                                const unsigned* __restrict__ ecv,
                                                const unsigned short* __restrict__ dense,
                                                const short* __restrict__ Mt,
                                                unsigned short* __restrict__ outU) {
    __shared__ unsigned lm[4][8][68];    // 8.7 KB; stride 68 words: 16B-aligned rows, <=2-way banks
    __shared__ unsigned short tr[32][64]; // 4 KB; chunk-XOR-swizzled h tile for MFMA
    int wave = threadIdx.x >> 6;
    int lane = threadIdx.x & 63;
    int s = lane >> 3, dq = lane & 7;
    int row = wave * 8 + s;                    // 0..31 node within block
    int r = blockIdx.x * 32 + row;             // 3125 * 32 == 100000
    int2 meta = rowmeta[r];
    int beg = meta.x, deg = meta.y;            // deg multiple of 4 (maybe 0)
    int degc = deg < 64 ? deg : 64;
    for (int e = dq; e < degc; e += 8)         // stage this row's packed edges
        lm[wave][s][e] = ecv[beg + e];
    __syncthreads();
    const unsigned* mp = lm[wave][s];
    float a0=0,a1=0,a2=0,a3=0,a4=0,a5=0,a6=0,a7=0;
    if (deg > 0) {
        uint4 w = *(const uint4*)mp;           // deg>0 => deg>=4, safe
        for (int e = 0; e < degc; e += 4) {
            uint4 wn = (e + 4 < degc) ? *(const uint4*)(mp + e + 4) : w;   // 1-ahead meta (lgkm)
            uint4 g0 = *(const uint4*)(dense + ((size_t)(w.x & 0x1FFFF) << 6) + (dq << 3));
            uint4 g1 = *(const uint4*)(dense + ((size_t)(w.y & 0x1FFFF) << 6) + (dq << 3));
            uint4 g2 = *(const uint4*)(dense + ((size_t)(w.z & 0x1FFFF) << 6) + (dq << 3));
            uint4 g3 = *(const uint4*)(dense + ((size_t)(w.w & 0x1FFFF) << 6) + (dq << 3));
            float v0 = upval(w.x), v1 = upval(w.y), v2 = upval(w.z), v3 = upval(w.w);
            a0=fmaf(v0,bflo(g0.x),a0); a1=fmaf(v0,bfhi(g0.x),a1); a2=fmaf(v0,bflo(g0.y),a2); a3=fmaf(v0,bfhi(g0.y),a3);
            a4=fmaf(v0,bflo(g0.z),a4); a5=fmaf(v0,bfhi(g0.z),a5); a6=fmaf(v0,bflo(g0.w),a6); a7=fmaf(v0,bfhi(g0.w),a7);
            a0=fmaf(v1,bflo(g1.x),a0); a1=fmaf(v1,bfhi(g1.x),a1); a2=fmaf(v1,bflo(g1.y),a2); a3=fmaf(v1,bfhi(g1.y),a3);
            a4=fmaf(v1,bflo(g1.z),a4); a5=fmaf(v1,bfhi(g1.z),a5); a6=fmaf(v1,bflo(g1.w),a6); a7=fmaf(v1,bfhi(g1.w),a7);
            a0=fmaf(v2,bflo(g2.x),a0); a1=fmaf(v2,bfhi(g2.x),a1); a2=fmaf(v2,bflo(g2.y),a2); a3=fmaf(v2,bfhi(g2.y),a3);
            a4=fmaf(v2,bflo(g2.z),a4); a5=fmaf(v2,bfhi(g2.z),a5); a6=fmaf(v2,bflo(g2.w),a6); a7=fmaf(v2,bfhi(g2.w),a7);
            a0=fmaf(v3,bflo(g3.x),a0); a1=fmaf(v3,bfhi(g3.x),a1); a2=fmaf(v3,bflo(g3.y),a2); a3=fmaf(v3,bfhi(g3.y),a3);
            a4=fmaf(v3,bflo(g3.z),a4); a5=fmaf(v3,bfhi(g3.z),a5); a6=fmaf(v3,bflo(g3.w),a6); a7=fmaf(v3,bfhi(g3.w),a7);
            w = wn;
        }
        for (int e = 64; e < deg; ++e) {       // rare tail (deg > 64)
            unsigned we = ecv[beg + e];
            uint4 g = *(const uint4*)(dense + ((size_t)(we & 0x1FFFF) << 6) + (dq << 3));
            float v = upval(we);
            a0=fmaf(v,bflo(g.x),a0); a1=fmaf(v,bfhi(g.x),a1); a2=fmaf(v,bflo(g.y),a2); a3=fmaf(v,bfhi(g.y),a3);
            a4=fmaf(v,bflo(g.z),a4); a5=fmaf(v,bfhi(g.z),a5); a6=fmaf(v,bflo(g.w),a6); a7=fmaf(v,bfhi(g.w),a7);
        }
    }
    // h = relu(agg) -> bf16, store 16B chunk at XOR-swizzled column (uniform bank spread)
    uint4 o;
    o.x = (unsigned short)f2bf(fmaxf(a0,0.f)) | ((unsigned)(unsigned short)f2bf(fmaxf(a1,0.f)) << 16);
    o.y = (unsigned short)f2bf(fmaxf(a2,0.f)) | ((unsigned)(unsigned short)f2bf(fmaxf(a3,0.f)) << 16);
    o.z = (unsigned short)f2bf(fmaxf(a4,0.f)) | ((unsigned)(unsigned short)f2bf(fmaxf(a5,0.f)) << 16);
    o.w = (unsigned short)f2bf(fmaxf(a6,0.f)) | ((unsigned)(unsigned short)f2bf(fmaxf(a7,0.f)) << 16);
    *(uint4*)(&tr[row][(dq ^ s) << 3]) = o;
    __syncthreads();
    // ---- u = h @ M: per wave, 1 node-tile x 2 n-tiles x 2 k-steps ----
    int m = lane & 15;
    int q = lane >> 4;
    int nt = wave >> 1;                  // node tile 0/1 (nodes nt*16..+15)
    int tb = (wave & 1) << 1;            // n-tiles {0,1} or {2,3}
    int arow = nt * 16 + m;
    f32x4 c0 = {0,0,0,0}, c1 = {0,0,0,0};
#pragma unroll
    for (int kb = 0; kb < 2; ++kb) {
        int ch = kb * 4 + q;                                    // 16B chunk index of k0
        bf16x8 af = *(const bf16x8*)(&tr[arow][(ch ^ (arow & 7)) << 3]);
        int k0 = kb * 32 + q * 8;
        bf16x8 bf0 = *(const bf16x8*)(Mt + ((tb + 0) * 16 + m) * HID_DIM + k0);
        bf16x8 bf1 = *(const bf16x8*)(Mt + ((tb + 1) * 16 + m) * HID_DIM + k0);
        c0 = __builtin_amdgcn_mfma_f32_16x16x32_bf16(af, bf0, c0, 0, 0, 0);
        c1 = __builtin_amdgcn_mfma_f32_16x16x32_bf16(af, bf1, c1, 0, 0, 0);
    }
#pragma unroll
    for (int rr = 0; rr < 4; ++rr) {
        int node = blockIdx.x * 32 + nt * 16 + q * 4 + rr;      // C/D: col=lane&15, row=q*4+rr
        outU[(size_t)node * HID_DIM + (tb + 0) * 16 + m] = (unsigned short)f2bf(c0[rr]);
        outU[(size_t)node * HID_DIM + (tb + 1) * 16 + m] = (unsigned short)f2bf(c1[rr]);
    }
}

// ---------------- SpMM2 + classifier epilogue (v5 body + intra-subgroup log-softmax) ----------------
__global__ __launch_bounds__(256) void spmm_cls(const int2* __restrict__ rowmeta,
                                                const unsigned* __restrict__ ecv,
                                                const unsigned short* __restrict__ dense,
                                                const float* __restrict__ bv,
                                                const float* __restrict__ bc,
                                                float* __restrict__ outF) {
    __shared__ unsigned lm[4][8][68];
    int wave = threadIdx.x >> 6;
    int lane = threadIdx.x & 63;
    int s = lane >> 3, dq = lane & 7;
    int r = (blockIdx.x * 4 + wave) * 8 + s;
    float4 bv0 = {0,0,0,0}, bv1 = {0,0,0,0}, bc0 = {0,0,0,0}, bc1 = {0,0,0,0};
    if (dq < 5) {
        bv0 = *(const float4*)(bv + dq * 8);  bv1 = *(const float4*)(bv + dq * 8 + 4);
        bc0 = *(const float4*)(bc + dq * 8);  bc1 = *(const float4*)(bc + dq * 8 + 4);
    }
    int2 meta = rowmeta[r];
    int beg = meta.x, deg = meta.y;
    int degc = deg < 64 ? deg : 64;
    for (int e = dq; e < degc; e += 8)
        lm[wave][s][e] = ecv[beg + e];
    __syncthreads();
    const unsigned* mp = lm[wave][s];
    float a0=0,a1=0,a2=0,a3=0,a4=0,a5=0,a6=0,a7=0, asum=0;
    if (deg > 0) {
        uint4 w = *(const uint4*)mp;
        for (int e = 0; e < degc; e += 4) {
            uint4 wn = (e + 4 < degc) ? *(const uint4*)(mp + e + 4) : w;
            uint4 g0 = *(const uint4*)(dense + ((size_t)(w.x & 0x1FFFF) << 6) + (dq << 3));
            uint4 g1 = *(const uint4*)(dense + ((size_t)(w.y & 0x1FFFF) << 6) + (dq << 3));
            uint4 g2 = *(const uint4*)(dense + ((size_t)(w.z & 0x1FFFF) << 6) + (dq << 3));
            uint4 g3 = *(const uint4*)(dense + ((size_t)(w.w & 0x1FFFF) << 6) + (dq << 3));
            float v0 = upval(w.x), v1 = upval(w.y), v2 = upval(w.z), v3 = upval(w.w);
            asum += v0 + v1 + v2 + v3;
            a0=fmaf(v0,bflo(g0.x),a0); a1=fmaf(v0,bfhi(g0.x),a1); a2=fmaf(v0,bflo(g0.y),a2); a3=fmaf(v0,bfhi(g0.y),a3);
            a4=fmaf(v0,bflo(g0.z),a4); a5=fmaf(v0,bfhi(g0.z),a5); a6=fmaf(v0,bflo(g0.w),a6); a7=fmaf(v0,bfhi(g0.w),a7);
            a0=fmaf(v1,bflo(g1.x),a0); a1=fmaf(v1,bfhi(g1.x),a1); a2=fmaf(v1,bflo(g1.y),a2); a3=fmaf(v1,bfhi(g1.y),a3);
            a4=fmaf(v1,bflo(g1.z),a4); a5=fmaf(v1,bfhi(g1.z),a5); a6=fmaf(v1,bflo(g1.w),a6); a7=fmaf(v1,bfhi(g1.w),a7);
            a0=fmaf(v2,bflo(g2.x),a0); a1=fmaf(v2,bfhi(g2.x),a1); a2=fmaf(v2,bflo(g2.y),a2); a3=fmaf(v2,bfhi(g2.y),a3);
            a4=fmaf(v2,bflo(g2.z),a4); a5=fmaf(v2,bfhi(g2.z),a5); a6=fmaf(v2,bflo(g2.w),a6); a7=fmaf(v2,bfhi(g2.w),a7);
            a0=fmaf(v3,bflo(g3.x),a0); a1=fmaf(v3,bfhi(g3.x),a1); a2=fmaf(v3,bflo(g3.y),a2); a3=fmaf(v3,bfhi(g3.y),a3);
            a4=fmaf(v3,bflo(g3.z),a4); a5=fmaf(v3,bfhi(g3.z),a5); a6=fmaf(v3,bflo(g3.w),a6); a7=fmaf(v3,bfhi(g3.w),a7);
            w = wn;
        }
        for (int e = 64; e < deg; ++e) {
            unsigned we = ecv[beg + e];
            uint4 g = *(const uint4*)(dense + ((size_t)(we & 0x1FFFF) << 6) + (dq << 3));
            float v = upval(we);
            asum += v;
            a0=fmaf(v,bflo(g.x),a0); a1=fmaf(v,bfhi(g.x),a1); a2=fmaf(v,bflo(g.y),a2); a3=fmaf(v,bfhi(g.y),a3);
            a4=fmaf(v,bflo(g.z),a4); a5=fmaf(v,bfhi(g.z),a5); a6=fmaf(v,bflo(g.w),a6); a7=fmaf(v,bfhi(g.w),a7);
        }
    }
    // logits for this lane's dim octet (asum is complete per-lane; no reduction needed)
    float l0 = fmaf(asum, bv0.x, a0) + bc0.x;
    float l1 = fmaf(asum, bv0.y, a1) + bc0.y;
    float l2 = fmaf(asum, bv0.z, a2) + bc0.z;
    float l3 = fmaf(asum, bv0.w, a3) + bc0.w;
    float l4 = fmaf(asum, bv1.x, a4) + bc1.x;
    float l5 = fmaf(asum, bv1.y, a5) + bc1.y;
    float l6 = fmaf(asum, bv1.z, a6) + bc1.z;
    float l7 = fmaf(asum, bv1.w, a7) + bc1.w;
    float mx = -1e30f;
    if (dq < 5)
        mx = fmaxf(fmaxf(fmaxf(l0, l1), fmaxf(l2, l3)),
                   fmaxf(fmaxf(l4, l5), fmaxf(l6, l7)));
#pragma unroll
    for (int off = 1; off < 8; off <<= 1) mx = fmaxf(mx, __shfl_xor(mx, off));
    float ss = 0.f;
    if (dq < 5)
        ss = __expf(l0 - mx) + __expf(l1 - mx) + __expf(l2 - mx) + __expf(l3 - mx)
           + __expf(l4 - mx) + __expf(l5 - mx) + __expf(l6 - mx) + __expf(l7 - mx);
#pragma unroll
    for (int off = 1; off < 8; off <<= 1) ss += __shfl_xor(ss, off);
    float lse = mx + __logf(ss);
    if (dq < 5) {
        float4 o0 = {l0 - lse, l1 - lse, l2 - lse, l3 - lse};
        float4 o1 = {l4 - lse, l5 - lse, l6 - lse, l7 - lse};
        float* dst = outF + (size_t)r * N_CLASSES + dq * 8;
        *(float4*)(dst) = o0;
        *(float4*)(dst + 4) = o1;
    }
}

extern "C" void kernel_launch(void* const* d_in, const int* in_sizes, int n_in,
                              void* d_out, int out_size, void* d_ws, size_t ws_size,
                              hipStream_t stream) {
    const float* x    = (const float*)d_in[0];
    const int*   erow = (const int*)  d_in[1];
    const int*   ecol = (const int*)  d_in[2];
    const float* eval = (const float*)d_in[3];
    const float* W1   = (const float*)d_in[4];
    const float* b1   = (const float*)d_in[5];
    const float* W2   = (const float*)d_in[6];
    const float* b2   = (const float*)d_in[7];
    const float* Wc   = (const float*)d_in[8];
    const float* bc   = (const float*)d_in[9];
    float* out = (float*)d_out;

    // ---- workspace layout ----
    char* ws = (char*)d_ws;
    size_t off = 0;
    auto alloc = [&](size_t bytes) { char* p = ws + off; off += (bytes + 255) & ~(size_t)255; return p; };
    unsigned short* bufA = (unsigned short*)alloc((size_t)N_NODES * HID_DIM * sizeof(short)); // 12.8 MB (h from gemm1)
    unsigned short* bufB = (unsigned short*)alloc((size_t)N_NODES * HID_DIM * sizeof(short)); // 12.8 MB (u from spmm1_mm)
    int2*     tmp     = (int2*)    alloc((size_t)NBUCK * BCAP * sizeof(int2));     // 17.6 MB
    unsigned* tmp2    = (unsigned*)alloc((size_t)NBUCK * BCAP * sizeof(unsigned)); //  8.8 MB
    int2*     rowmeta = (int2*)    alloc((size_t)N_NODES * sizeof(int2));          //  0.8 MB
    int*      bcnt    = (int*)     alloc(NBUCK * sizeof(int));
    short*    W1t     = (short*)   alloc((size_t)IN_DIM * HID_DIM * sizeof(short));
    short*    Mt      = (short*)   alloc((size_t)HID_DIM * HID_DIM * sizeof(short));
    float*    bv      = (float*)   alloc(64 * sizeof(float));

    const int tile_grid = (N_NODES + 63) / 64;       // 1563
    const int spmm_grid = N_NODES / 32;              // 3125 (4 waves x 8 rows, exact)

    // bcnt must be zero before prep_parta's cross-block atomics (memset node is capturable)
    hipMemsetAsync(bcnt, 0, NBUCK * sizeof(int), stream);
    // fused: part_a (blocks 0..249) || weight prep (blocks 250..257)
    prep_parta<<<GRID_A + 8, PBLK, 0, stream>>>(erow, ecol, eval, bcnt, tmp,
                                                W1, W2, Wc, b2, W1t, Mt, bv);
    // fused: part_b (blocks 0..NBUCK-1) || gemm1 (blocks NBUCK..NBUCK+1562)
    part_b_gemm1<<<NBUCK + tile_grid, 256, 0, stream>>>(bcnt, tmp, tmp2, rowmeta,
                                                        x, W1t, b1, bufA);
    // layer-1 aggregate + relu + layer-2 matmul (u = relu(agg) @ (W2@Wc)), fused
    spmm1_mm<<<spmm_grid, 256, 0, stream>>>(rowmeta, tmp2, bufA, Mt, bufB);
    // layer-2 aggregate + classifier bias/softmax
    spmm_cls<<<spmm_grid, 256, 0, stream>>>(rowmeta, tmp2, bufB, bv, bc, out);
}

// Round 3
// 217.033 us; speedup vs baseline: 1.2355x; 1.0704x over previous
//
#include <hip/hip_runtime.h>

#define N_NODES   100000
#define N_EDGES   1600000
#define IN_DIM    128
#define HID_DIM   64
#define N_CLASSES 40
#define U_DIM     40       // u = relu(h)@(W2@Wc) has only 40 live columns

#define NBUCK 782          // ceil(100000 / 128) coarse buckets, bucket = row >> 7
#define BCAP  2816         // bucket capacity incl. pad-to-4
#define EPB   6400         // edges per block in pass A
#define PBLK  1024         // part_a block size
#define GRID_A 250         // N_EDGES / EPB exactly

typedef __attribute__((ext_vector_type(8))) short bf16x8;
typedef __attribute__((ext_vector_type(4))) float f32x4;

__device__ inline short f2bf(float f) {
    unsigned u = __float_as_uint(f);
    unsigned r = (u + 0x7FFFu + ((u >> 16) & 1u)) >> 16;   // RNE
    return (short)r;
}
__device__ inline float bflo(unsigned w) { return __uint_as_float(w << 16); }
__device__ inline float bfhi(unsigned w) { return __uint_as_float(w & 0xFFFF0000u); }
// packed edge: bits[16:0] = col, bits[31:17] = val as unsigned bf15 (sign dropped, vals >= 0)
__device__ inline float upval(unsigned w) { return __uint_as_float((w >> 17) << 16); }

// ---------------- fused: weight prep (blocks >= GRID_A) || Pass A bucket sort ----------------
// prep: W1t bf16 [64][128]; Mt = (W2@Wc)^T bf16 [64][64] (rows 40..63 zero); bv = b2@Wc fp32 [40]
// part_a payload: x = (localrow7 << 17) | col17 ; y = (valbf15 << 10) | bucket10
// bcnt must be zeroed by hipMemsetAsync BEFORE this kernel (cross-block ordering).
__global__ __launch_bounds__(PBLK) void prep_parta(const int* __restrict__ erow,
                                                   const int* __restrict__ ecol,
                                                   const float* __restrict__ eval,
                                                   int* __restrict__ bcnt,
                                                   int2* __restrict__ tmp,
                                                   const float* __restrict__ W1,
                                                   const float* __restrict__ W2,
                                                   const float* __restrict__ Wc,
                                                   const float* __restrict__ b2,
                                                   short* __restrict__ W1t,
                                                   short* __restrict__ Mt,
                                                   float* __restrict__ bv) {
    __shared__ int2 pay[EPB];                                    // 51.2 KB
    __shared__ int hist[NBUCK], lbase[NBUCK], cur[NBUCK], dofs[NBUCK], scan[NBUCK]; // 15.6 KB
    int tid = threadIdx.x;
    if (blockIdx.x >= GRID_A) {
        // ---------- weight prep (8 blocks) ----------
        int pb = blockIdx.x - GRID_A;
        {   // W1t: 8192 entries, exactly one per thread across 8 blocks
            int i = pb * PBLK + tid;
            int n = i >> 7, k = i & 127;
            W1t[i] = f2bf(W1[k * HID_DIM + n]);
        }
        if (pb == 0) {
            for (int idx = tid; idx < HID_DIM * HID_DIM; idx += PBLK) {
                int n = idx >> 6, i = idx & 63;    // Mt[n][i] = M[i][n] = sum_j W2[i][j]*Wc[j][n]
                float acc = 0.f;
                if (n < N_CLASSES)
                    for (int j = 0; j < HID_DIM; ++j)
                        acc = fmaf(W2[i * HID_DIM + j], Wc[j * N_CLASSES + n], acc);
                Mt[n * HID_DIM + i] = f2bf(acc);
            }
        }
        if (pb == 1 && tid < N_CLASSES) {
            float acc = 0.f;
            for (int j = 0; j < HID_DIM; ++j)
                acc = fmaf(b2[j], Wc[j * N_CLASSES + tid], acc);
            bv[tid] = acc;
        }
        return;
    }
    // ---------- Pass A ----------
    int e0 = blockIdx.x * EPB;
    for (int i = tid; i < NBUCK; i += PBLK) { hist[i] = 0; cur[i] = 0; }
    __syncthreads();
    for (int i = tid; i < EPB; i += PBLK)
        atomicAdd(&hist[erow[e0 + i] >> 7], 1);
    __syncthreads();
    for (int i = tid; i < NBUCK; i += PBLK) {
        int n = hist[i];
        dofs[i] = i * BCAP + (n ? atomicAdd(&bcnt[i], n) : 0);
        scan[i] = n;
    }
    __syncthreads();
    for (int off = 1; off < NBUCK; off <<= 1) {
        int t = 0;
        if (tid < NBUCK && tid >= off) t = scan[tid - off];
        __syncthreads();
        if (tid < NBUCK) scan[tid] += t;
        __syncthreads();
    }
    if (tid < NBUCK) {
        lbase[tid] = scan[tid] - hist[tid];
        dofs[tid] -= lbase[tid];
    }
    __syncthreads();
    for (int i = tid; i < EPB; i += PBLK) {
        int e = e0 + i;
        int r = erow[e];
        int b = r >> 7;
        int p = lbase[b] + atomicAdd(&cur[b], 1);
        unsigned u = __float_as_uint(eval[e]);
        unsigned vb = ((u + 0x7FFFu + ((u >> 16) & 1u)) >> 16) & 0x7FFFu;  // bf15 RNE, sign dropped
        pay[p] = make_int2(((r & 127) << 17) | ecol[e], (int)((vb << 10) | (unsigned)b));
    }
    __syncthreads();
    for (int p = tid; p < EPB; p += PBLK) {
        int2 v = pay[p];
        int b = (unsigned)v.y & 1023u;
        int dest = dofs[b] + p;
        if (dest < (b + 1) * BCAP)
            tmp[dest] = v;
    }
}

// ---------------- fused: Pass B (blocks < NBUCK) || GEMM1 MFMA (blocks >= NBUCK) ----------------
// Pass B: sort bucket by local row, pad to mult-of-4, pack to 4 B
// GEMM1:  hbf[n,64] = bf16(x[n,128] @ W1 + b1)   (independent of the edge sort)
__global__ __launch_bounds__(256) void part_b_gemm1(const int* __restrict__ bcnt,
                                                    const int2* __restrict__ tmp,
                                                    unsigned* __restrict__ tmp2,
                                                    int2* __restrict__ rowmeta,
                                                    const float* __restrict__ x,
                                                    const short* __restrict__ W1t,
                                                    const float* __restrict__ b1,
                                                    unsigned short* __restrict__ outH) {
    __shared__ int2 ein[BCAP];           // 22.5 KB
    __shared__ unsigned eout[BCAP];      // 11.3 KB
    __shared__ int hist[128], pad[128], basep[128], cur[128], scan[128];
    if (blockIdx.x < NBUCK) {
        // ---------- Pass B ----------
        int b = blockIdx.x;
        int nb = bcnt[b]; if (nb > BCAP) nb = BCAP;
        for (int i = threadIdx.x; i < nb; i += 256) ein[i] = tmp[(size_t)b * BCAP + i];
        if (threadIdx.x < 128) { hist[threadIdx.x] = 0; cur[threadIdx.x] = 0; }
        __syncthreads();
        for (int i = threadIdx.x; i < nb; i += 256)
            atomicAdd(&hist[(ein[i].x >> 17) & 127], 1);
        __syncthreads();
        if (threadIdx.x < 128) {
            pad[threadIdx.x] = (hist[threadIdx.x] + 3) & ~3;     // pad to mult-of-4
            scan[threadIdx.x] = pad[threadIdx.x];
        }
        __syncthreads();
        for (int off = 1; off < 128; off <<= 1) {
            int t = 0;
            if (threadIdx.x < 128 && threadIdx.x >= off) t = scan[threadIdx.x - off];
            __syncthreads();
            if (threadIdx.x < 128) scan[threadIdx.x] += t;
            __syncthreads();
        }
        if (threadIdx.x < 128) basep[threadIdx.x] = scan[threadIdx.x] - pad[threadIdx.x];
        __syncthreads();
        int ntot = scan[127]; if (ntot > BCAP) ntot = BCAP;
        for (int i = threadIdx.x; i < nb; i += 256) {
            int lr = (ein[i].x >> 17) & 127;
            int p = basep[lr] + atomicAdd(&cur[lr], 1);
            if (p < BCAP) {
                unsigned vb = ((unsigned)ein[i].y >> 10) & 0x7FFFu;      // already bf15
                eout[p] = (vb << 17) | (unsigned)(ein[i].x & 0x1FFFF);
            }
        }
        __syncthreads();
        if (threadIdx.x < 128) {
            int pe = basep[threadIdx.x] + pad[threadIdx.x];
            for (int p = basep[threadIdx.x] + hist[threadIdx.x]; p < pe && p < BCAP; ++p)
                eout[p] = 0u;                 // col 0, val +0.0
        }
        __syncthreads();
        for (int i = threadIdx.x; i < ntot; i += 256) tmp2[(size_t)b * BCAP + i] = eout[i];
        if (threadIdx.x < 128) {
            int r = b * 128 + threadIdx.x;
            if (r < N_NODES)
                rowmeta[r] = make_int2(b * BCAP + basep[threadIdx.x], pad[threadIdx.x]);
        }
    } else {
        // ---------- GEMM1 (MFMA) ----------
        int gb = blockIdx.x - NBUCK;
        int wave = threadIdx.x >> 6;
        int lane = threadIdx.x & 63;
        int node0 = gb * 64 + wave * 16;
        if (node0 >= N_NODES) return;
        int m = lane & 15;
        int q = lane >> 4;
        const float* xrow = x + (size_t)(node0 + m) * IN_DIM;
        f32x4 acc0 = {0,0,0,0}, acc1 = {0,0,0,0}, acc2 = {0,0,0,0}, acc3 = {0,0,0,0};
#pragma unroll
        for (int kb = 0; kb < 4; ++kb) {
            int k0 = kb * 32 + q * 8;
            float4 a0 = *(const float4*)(xrow + k0);
            float4 a1 = *(const float4*)(xrow + k0 + 4);
            bf16x8 af;
            af[0]=f2bf(a0.x); af[1]=f2bf(a0.y); af[2]=f2bf(a0.z); af[3]=f2bf(a0.w);
            af[4]=f2bf(a1.x); af[5]=f2bf(a1.y); af[6]=f2bf(a1.z); af[7]=f2bf(a1.w);
            bf16x8 bf0 = *(const bf16x8*)(W1t + ( 0 + m) * IN_DIM + k0);
            bf16x8 bf1 = *(const bf16x8*)(W1t + (16 + m) * IN_DIM + k0);
            bf16x8 bf2 = *(const bf16x8*)(W1t + (32 + m) * IN_DIM + k0);
            bf16x8 bf3 = *(const bf16x8*)(W1t + (48 + m) * IN_DIM + k0);
            acc0 = __builtin_amdgcn_mfma_f32_16x16x32_bf16(af, bf0, acc0, 0, 0, 0);
            acc1 = __builtin_amdgcn_mfma_f32_16x16x32_bf16(af, bf1, acc1, 0, 0, 0);
            acc2 = __builtin_amdgcn_mfma_f32_16x16x32_bf16(af, bf2, acc2, 0, 0, 0);
            acc3 = __builtin_amdgcn_mfma_f32_16x16x32_bf16(af, bf3, acc3, 0, 0, 0);
        }
        f32x4 accs[4] = {acc0, acc1, acc2, acc3};
#pragma unroll
        for (int t = 0; t < 4; ++t) {
            float bias = b1[t * 16 + m];
#pragma unroll
            for (int r = 0; r < 4; ++r) {
                int node = node0 + q * 4 + r;            // C/D: col=lane&15, row=q*4+r
                outH[(size_t)node * HID_DIM + t * 16 + m] = (unsigned short)f2bf(accs[t][r] + bias);
            }
        }
    }
}

#define FMA8(v,g) \
    a0=fmaf(v,bflo(g.x),a0); a1=fmaf(v,bfhi(g.x),a1); a2=fmaf(v,bflo(g.y),a2); a3=fmaf(v,bfhi(g.y),a3); \
    a4=fmaf(v,bflo(g.z),a4); a5=fmaf(v,bfhi(g.z),a5); a6=fmaf(v,bflo(g.w),a6); a7=fmaf(v,bfhi(g.w),a7);

// ---------------- SpMM1 + fused layer-2 matmul ----------------
// Gather loop: 8 edges/iter (8 x 16B gathers in flight for MLP), 4-edge prologue for odd quads.
// Epilogue: h = relu(agg) -> bf16 -> XOR-swizzled LDS [32 nodes][64 dims], barrier, then
// u = h @ M via 4 MFMAs/wave, stored 40-wide (cols 40..63 of u are structurally zero).
__global__ __launch_bounds__(256) void spmm1_mm(const int2* __restrict__ rowmeta,
                                                const unsigned* __restrict__ ecv,
                                                const unsigned short* __restrict__ dense,
                                                const short* __restrict__ Mt,
                                                unsigned short* __restrict__ outU) {
    __shared__ unsigned lm[4][8][68];    // 8.7 KB; stride 68 words: 16B-aligned rows, <=2-way banks
    __shared__ unsigned short tr[32][64]; // 4 KB; chunk-XOR-swizzled h tile for MFMA
    int wave = threadIdx.x >> 6;
    int lane = threadIdx.x & 63;
    int s = lane >> 3, dq = lane & 7;
    int row = wave * 8 + s;                    // 0..31 node within block
    int r = blockIdx.x * 32 + row;             // 3125 * 32 == 100000
    int2 meta = rowmeta[r];
    int beg = meta.x, deg = meta.y;            // deg multiple of 4 (maybe 0)
    int degc = deg < 64 ? deg : 64;
    for (int e = dq; e < degc; e += 8)         // stage this row's packed edges
        lm[wave][s][e] = ecv[beg + e];
    __syncthreads();
    const unsigned* mp = lm[wave][s];
    float a0=0,a1=0,a2=0,a3=0,a4=0,a5=0,a6=0,a7=0;
    if (deg > 0) {
        int e = 0;
        if (degc & 4) {                        // odd quad count: 4-edge prologue
            uint4 w = *(const uint4*)mp;
            uint4 g0 = *(const uint4*)(dense + ((size_t)(w.x & 0x1FFFF) << 6) + (dq << 3));
            uint4 g1 = *(const uint4*)(dense + ((size_t)(w.y & 0x1FFFF) << 6) + (dq << 3));
            uint4 g2 = *(const uint4*)(dense + ((size_t)(w.z & 0x1FFFF) << 6) + (dq << 3));
            uint4 g3 = *(const uint4*)(dense + ((size_t)(w.w & 0x1FFFF) << 6) + (dq << 3));
            float v0 = upval(w.x), v1 = upval(w.y), v2 = upval(w.z), v3 = upval(w.w);
            FMA8(v0,g0); FMA8(v1,g1); FMA8(v2,g2); FMA8(v3,g3);
            e = 4;
        }
        for (; e < degc; e += 8) {             // 8-wide: 8 gathers in flight
            uint4 wa = *(const uint4*)(mp + e);
            uint4 wb = *(const uint4*)(mp + e + 4);
            uint4 g0 = *(const uint4*)(dense + ((size_t)(wa.x & 0x1FFFF) << 6) + (dq << 3));
            uint4 g1 = *(const uint4*)(dense + ((size_t)(wa.y & 0x1FFFF) << 6) + (dq << 3));
            uint4 g2 = *(const uint4*)(dense + ((size_t)(wa.z & 0x1FFFF) << 6) + (dq << 3));
            uint4 g3 = *(const uint4*)(dense + ((size_t)(wa.w & 0x1FFFF) << 6) + (dq << 3));
            uint4 g4 = *(const uint4*)(dense + ((size_t)(wb.x & 0x1FFFF) << 6) + (dq << 3));
            uint4 g5 = *(const uint4*)(dense + ((size_t)(wb.y & 0x1FFFF) << 6) + (dq << 3));
            uint4 g6 = *(const uint4*)(dense + ((size_t)(wb.z & 0x1FFFF) << 6) + (dq << 3));
            uint4 g7 = *(const uint4*)(dense + ((size_t)(wb.w & 0x1FFFF) << 6) + (dq << 3));
            float v0 = upval(wa.x), v1 = upval(wa.y), v2 = upval(wa.z), v3 = upval(wa.w);
            float v4 = upval(wb.x), v5 = upval(wb.y), v6 = upval(wb.z), v7 = upval(wb.w);
            FMA8(v0,g0); FMA8(v1,g1); FMA8(v2,g2); FMA8(v3,g3);
            FMA8(v4,g4); FMA8(v5,g5); FMA8(v6,g6); FMA8(v7,g7);
        }
        for (int e2 = 64; e2 < deg; ++e2) {    // rare tail (deg > 64)
            unsigned we = ecv[beg + e2];
            uint4 g = *(const uint4*)(dense + ((size_t)(we & 0x1FFFF) << 6) + (dq << 3));
            float v = upval(we);
            FMA8(v,g);
        }
    }
    // h = relu(agg) -> bf16, store 16B chunk at XOR-swizzled column (uniform bank spread)
    uint4 o;
    o.x = (unsigned short)f2bf(fmaxf(a0,0.f)) | ((unsigned)(unsigned short)f2bf(fmaxf(a1,0.f)) << 16);
    o.y = (unsigned short)f2bf(fmaxf(a2,0.f)) | ((unsigned)(unsigned short)f2bf(fmaxf(a3,0.f)) << 16);
    o.z = (unsigned short)f2bf(fmaxf(a4,0.f)) | ((unsigned)(unsigned short)f2bf(fmaxf(a5,0.f)) << 16);
    o.w = (unsigned short)f2bf(fmaxf(a6,0.f)) | ((unsigned)(unsigned short)f2bf(fmaxf(a7,0.f)) << 16);
    *(uint4*)(&tr[row][(dq ^ s) << 3]) = o;
    __syncthreads();
    // ---- u = h @ M: per wave, 1 node-tile x 2 n-tiles x 2 k-steps ----
    int m = lane & 15;
    int q = lane >> 4;
    int nt = wave >> 1;                  // node tile 0/1 (nodes nt*16..+15)
    int tb = (wave & 1) << 1;            // n-tiles {0,1} or {2,3}
    int arow = nt * 16 + m;
    f32x4 c0 = {0,0,0,0}, c1 = {0,0,0,0};
#pragma unroll
    for (int kb = 0; kb < 2; ++kb) {
        int ch = kb * 4 + q;                                    // 16B chunk index of k0
        bf16x8 af = *(const bf16x8*)(&tr[arow][(ch ^ (arow & 7)) << 3]);
        int k0 = kb * 32 + q * 8;
        bf16x8 bf0 = *(const bf16x8*)(Mt + ((tb + 0) * 16 + m) * HID_DIM + k0);
        bf16x8 bf1 = *(const bf16x8*)(Mt + ((tb + 1) * 16 + m) * HID_DIM + k0);
        c0 = __builtin_amdgcn_mfma_f32_16x16x32_bf16(af, bf0, c0, 0, 0, 0);
        c1 = __builtin_amdgcn_mfma_f32_16x16x32_bf16(af, bf1, c1, 0, 0, 0);
    }
#pragma unroll
    for (int rr = 0; rr < 4; ++rr) {
        int node = blockIdx.x * 32 + nt * 16 + q * 4 + rr;      // C/D: col=lane&15, row=q*4+rr
        int col0 = tb * 16 + m;          // 0..15 or 32..47
        int col1 = col0 + 16;            // 16..31 or 48..63
        if (col0 < U_DIM)
            outU[(size_t)node * U_DIM + col0] = (unsigned short)f2bf(c0[rr]);
        if (col1 < U_DIM)
            outU[(size_t)node * U_DIM + col1] = (unsigned short)f2bf(c1[rr]);
    }
}

// ---------------- SpMM2 + classifier epilogue ----------------
// dense (= u) is 40-wide: lanes dq<5 gather real octets; dq>=5 clamp to octet 0 (same
// cacheline as lane dq=0 -> no extra traffic, no divergence); their a's are unused.
__global__ __launch_bounds__(256) void spmm_cls(const int2* __restrict__ rowmeta,
                                                const unsigned* __restrict__ ecv,
                                                const unsigned short* __restrict__ dense,
                                                const float* __restrict__ bv,
                                                const float* __restrict__ bc,
                                                float* __restrict__ outF) {
    __shared__ unsigned lm[4][8][68];
    int wave = threadIdx.x >> 6;
    int lane = threadIdx.x & 63;
    int s = lane >> 3, dq = lane & 7;
    int dof = (dq < 5 ? dq : 0) << 3;          // clamped dim-octet offset (in shorts)
    int r = (blockIdx.x * 4 + wave) * 8 + s;
    float4 bv0 = {0,0,0,0}, bv1 = {0,0,0,0}, bc0 = {0,0,0,0}, bc1 = {0,0,0,0};
    if (dq < 5) {
        bv0 = *(const float4*)(bv + dq * 8);  bv1 = *(const float4*)(bv + dq * 8 + 4);
        bc0 = *(const float4*)(bc + dq * 8);  bc1 = *(const float4*)(bc + dq * 8 + 4);
    }
    int2 meta = rowmeta[r];
    int beg = meta.x, deg = meta.y;
    int degc = deg < 64 ? deg : 64;
    for (int e = dq; e < degc; e += 8)
        lm[wave][s][e] = ecv[beg + e];
    __syncthreads();
    const unsigned* mp = lm[wave][s];
    float a0=0,a1=0,a2=0,a3=0,a4=0,a5=0,a6=0,a7=0, asum=0;
    if (deg > 0) {
        int e = 0;
        if (degc & 4) {                        // odd quad count: 4-edge prologue
            uint4 w = *(const uint4*)mp;
            uint4 g0 = *(const uint4*)(dense + (size_t)(w.x & 0x1FFFF) * U_DIM + dof);
            uint4 g1 = *(const uint4*)(dense + (size_t)(w.y & 0x1FFFF) * U_DIM + dof);
            uint4 g2 = *(const uint4*)(dense + (size_t)(w.z & 0x1FFFF) * U_DIM + dof);
            uint4 g3 = *(const uint4*)(dense + (size_t)(w.w & 0x1FFFF) * U_DIM + dof);
            float v0 = upval(w.x), v1 = upval(w.y), v2 = upval(w.z), v3 = upval(w.w);
            asum += v0 + v1 + v2 + v3;
            FMA8(v0,g0); FMA8(v1,g1); FMA8(v2,g2); FMA8(v3,g3);
            e = 4;
        }
        for (; e < degc; e += 8) {             // 8-wide: 8 gathers in flight
            uint4 wa = *(const uint4*)(mp + e);
            uint4 wb = *(const uint4*)(mp + e + 4);
            uint4 g0 = *(const uint4*)(dense + (size_t)(wa.x & 0x1FFFF) * U_DIM + dof);
            uint4 g1 = *(const uint4*)(dense + (size_t)(wa.y & 0x1FFFF) * U_DIM + dof);
            uint4 g2 = *(const uint4*)(dense + (size_t)(wa.z & 0x1FFFF) * U_DIM + dof);
            uint4 g3 = *(const uint4*)(dense + (size_t)(wa.w & 0x1FFFF) * U_DIM + dof);
            uint4 g4 = *(const uint4*)(dense + (size_t)(wb.x & 0x1FFFF) * U_DIM + dof);
            uint4 g5 = *(const uint4*)(dense + (size_t)(wb.y & 0x1FFFF) * U_DIM + dof);
            uint4 g6 = *(const uint4*)(dense + (size_t)(wb.z & 0x1FFFF) * U_DIM + dof);
            uint4 g7 = *(const uint4*)(dense + (size_t)(wb.w & 0x1FFFF) * U_DIM + dof);
            float v0 = upval(wa.x), v1 = upval(wa.y), v2 = upval(wa.z), v3 = upval(wa.w);
            float v4 = upval(wb.x), v5 = upval(wb.y), v6 = upval(wb.z), v7 = upval(wb.w);
            asum += v0 + v1 + v2 + v3 + v4 + v5 + v6 + v7;
            FMA8(v0,g0); FMA8(v1,g1); FMA8(v2,g2); FMA8(v3,g3);
            FMA8(v4,g4); FMA8(v5,g5); FMA8(v6,g6); FMA8(v7,g7);
        }
        for (int e2 = 64; e2 < deg; ++e2) {
            unsigned we = ecv[beg + e2];
            uint4 g = *(const uint4*)(dense + (size_t)(we & 0x1FFFF) * U_DIM + dof);
            float v = upval(we);
            asum += v;
            FMA8(v,g);
        }
    }
    // logits for this lane's dim octet (asum is complete per-lane; no reduction needed)
    float l0 = fmaf(asum, bv0.x, a0) + bc0.x;
    float l1 = fmaf(asum, bv0.y, a1) + bc0.y;
    float l2 = fmaf(asum, bv0.z, a2) + bc0.z;
    float l3 = fmaf(asum, bv0.w, a3) + bc0.w;
    float l4 = fmaf(asum, bv1.x, a4) + bc1.x;
    float l5 = fmaf(asum, bv1.y, a5) + bc1.y;
    float l6 = fmaf(asum, bv1.z, a6) + bc1.z;
    float l7 = fmaf(asum, bv1.w, a7) + bc1.w;
    float mx = -1e30f;
    if (dq < 5)
        mx = fmaxf(fmaxf(fmaxf(l0, l1), fmaxf(l2, l3)),
                   fmaxf(fmaxf(l4, l5), fmaxf(l6, l7)));
#pragma unroll
    for (int off = 1; off < 8; off <<= 1) mx = fmaxf(mx, __shfl_xor(mx, off));
    float ss = 0.f;
    if (dq < 5)
        ss = __expf(l0 - mx) + __expf(l1 - mx) + __expf(l2 - mx) + __expf(l3 - mx)
           + __expf(l4 - mx) + __expf(l5 - mx) + __expf(l6 - mx) + __expf(l7 - mx);
#pragma unroll
    for (int off = 1; off < 8; off <<= 1) ss += __shfl_xor(ss, off);
    float lse = mx + __logf(ss);
    if (dq < 5) {
        float4 o0 = {l0 - lse, l1 - lse, l2 - lse, l3 - lse};
        float4 o1 = {l4 - lse, l5 - lse, l6 - lse, l7 - lse};
        float* dst = outF + (size_t)r * N_CLASSES + dq * 8;
        *(float4*)(dst) = o0;
        *(float4*)(dst + 4) = o1;
    }
}

extern "C" void kernel_launch(void* const* d_in, const int* in_sizes, int n_in,
                              void* d_out, int out_size, void* d_ws, size_t ws_size,
                              hipStream_t stream) {
    const float* x    = (const float*)d_in[0];
    const int*   erow = (const int*)  d_in[1];
    const int*   ecol = (const int*)  d_in[2];
    const float* eval = (const float*)d_in[3];
    const float* W1   = (const float*)d_in[4];
    const float* b1   = (const float*)d_in[5];
    const float* W2   = (const float*)d_in[6];
    const float* b2   = (const float*)d_in[7];
    const float* Wc   = (const float*)d_in[8];
    const float* bc   = (const float*)d_in[9];
    float* out = (float*)d_out;

    // ---- workspace layout ----
    char* ws = (char*)d_ws;
    size_t off = 0;
    auto alloc = [&](size_t bytes) { char* p = ws + off; off += (bytes + 255) & ~(size_t)255; return p; };
    unsigned short* bufA = (unsigned short*)alloc((size_t)N_NODES * HID_DIM * sizeof(short)); // 12.8 MB (h)
    unsigned short* bufB = (unsigned short*)alloc((size_t)N_NODES * U_DIM * sizeof(short));   //  8.0 MB (u, 40-wide)
    int2*     tmp     = (int2*)    alloc((size_t)NBUCK * BCAP * sizeof(int2));     // 17.6 MB
    unsigned* tmp2    = (unsigned*)alloc((size_t)NBUCK * BCAP * sizeof(unsigned)); //  8.8 MB
    int2*     rowmeta = (int2*)    alloc((size_t)N_NODES * sizeof(int2));          //  0.8 MB
    int*      bcnt    = (int*)     alloc(NBUCK * sizeof(int));
    short*    W1t     = (short*)   alloc((size_t)IN_DIM * HID_DIM * sizeof(short));
    short*    Mt      = (short*)   alloc((size_t)HID_DIM * HID_DIM * sizeof(short));
    float*    bv      = (float*)   alloc(64 * sizeof(float));

    const int tile_grid = (N_NODES + 63) / 64;       // 1563
    const int spmm_grid = N_NODES / 32;              // 3125 (4 waves x 8 rows, exact)

    // bcnt must be zero before prep_parta's cross-block atomics (memset node is capturable)
    hipMemsetAsync(bcnt, 0, NBUCK * sizeof(int), stream);
    // fused: part_a (blocks 0..249) || weight prep (blocks 250..257)
    prep_parta<<<GRID_A + 8, PBLK, 0, stream>>>(erow, ecol, eval, bcnt, tmp,
                                                W1, W2, Wc, b2, W1t, Mt, bv);
    // fused: part_b (blocks 0..NBUCK-1) || gemm1 (blocks NBUCK..NBUCK+1562)
    part_b_gemm1<<<NBUCK + tile_grid, 256, 0, stream>>>(bcnt, tmp, tmp2, rowmeta,
                                                        x, W1t, b1, bufA);
    // layer-1 aggregate + relu + layer-2 matmul (u = relu(agg) @ (W2@Wc)), fused
    spmm1_mm<<<spmm_grid, 256, 0, stream>>>(rowmeta, tmp2, bufA, Mt, bufB);
    // layer-2 aggregate (40-wide u) + classifier bias/softmax
    spmm_cls<<<spmm_grid, 256, 0, stream>>>(rowmeta, tmp2, bufB, bv, bc, out);
}